// Round 1
// baseline (1559.720 us; speedup 1.0000x reference)
//
#include <hip/hip_runtime.h>

#define C 128

__global__ void fill_deg(float* deg, int n) {
    int i = blockIdx.x * blockDim.x + threadIdx.x;
    if (i < n) deg[i] = 1.0f;  // self-loop
}

__global__ void scatter_deg(const int* __restrict__ ei, float* deg, int e) {
    int i = blockIdx.x * blockDim.x + threadIdx.x;
    if (i < e) atomicAdd(&deg[ei[e + i]], 1.0f);  // dst = ei[E + i]
}

__global__ void rsqrt_deg(const float* __restrict__ deg, float* dis, int n) {
    int i = blockIdx.x * blockDim.x + threadIdx.x;
    if (i < n) dis[i] = rsqrtf(deg[i]);
}

// xt[r][c] = sum_k x[r][k] * W[k][c].  128 threads = one channel each,
// register-tile 8 rows, k split into 2 tiles of 64 staged in LDS.
__global__ void gemm_xw(const float* __restrict__ x, const float* __restrict__ W,
                        float* __restrict__ xt, int n) {
    __shared__ float Wt[64 * C];   // 32 KB, W k-tile
    __shared__ float xs[8 * 64];   // 2 KB,  x tile (8 rows x 64 k)
    const int c = threadIdx.x;     // 0..127
    int r0 = blockIdx.x * 8;
    if (r0 >= n) return;
    float acc[8];
#pragma unroll
    for (int r = 0; r < 8; ++r) acc[r] = 0.0f;

    for (int kt = 0; kt < 2; ++kt) {
        // load W tile (coalesced, conflict-free: consecutive c -> consecutive addr)
        for (int i = c; i < 64 * C; i += C) Wt[i] = W[kt * 64 * C + i];
        // load x tile
        for (int i = c; i < 8 * 64; i += C) {
            int r = i >> 6, k = i & 63;
            int gr = r0 + r;
            xs[i] = (gr < n) ? x[gr * C + kt * 64 + k] : 0.0f;
        }
        __syncthreads();
#pragma unroll 8
        for (int k = 0; k < 64; ++k) {
            float wv = Wt[k * C + c];
#pragma unroll
            for (int r = 0; r < 8; ++r) acc[r] += xs[r * 64 + k] * wv;
        }
        __syncthreads();
    }
#pragma unroll
    for (int r = 0; r < 8; ++r) {
        int gr = r0 + r;
        if (gr < n) xt[gr * C + c] = acc[r];
    }
}

// out[i][c] = bias[c] + xt[i][c] * dis[i]^2   (self-loop folded in; also
// initializes the 0xAA-poisoned d_out before the atomic scatter)
__global__ void out_init(const float* __restrict__ xt, const float* __restrict__ dis,
                         const float* __restrict__ bias, float* __restrict__ out, int n) {
    int idx = blockIdx.x * blockDim.x + threadIdx.x;
    if (idx < n * C) {
        int row = idx >> 7;
        int c = idx & (C - 1);
        float d = dis[row];
        out[idx] = bias[c] + xt[idx] * d * d;
    }
}

// per edge: out[dst][:] += xt[src][:] * dis[src]*dis[dst]
// 32 threads per edge, float4 gather, scalar f32 atomics.
__global__ void edge_scatter(const int* __restrict__ ei, const float* __restrict__ xt,
                             const float* __restrict__ dis, float* __restrict__ out, int e) {
    long long idx = (long long)blockIdx.x * blockDim.x + threadIdx.x;
    if (idx >= (long long)e * 32) return;
    int eid = (int)(idx >> 5);
    int q = (int)(idx & 31);
    int src = ei[eid];
    int dst = ei[e + eid];
    float w = dis[src] * dis[dst];
    const float4 v = ((const float4*)xt)[src * 32 + q];
    float* o = out + (long long)dst * C + q * 4;
    atomicAdd(o + 0, v.x * w);
    atomicAdd(o + 1, v.y * w);
    atomicAdd(o + 2, v.z * w);
    atomicAdd(o + 3, v.w * w);
}

extern "C" void kernel_launch(void* const* d_in, const int* in_sizes, int n_in,
                              void* d_out, int out_size, void* d_ws, size_t ws_size,
                              hipStream_t stream) {
    const float* x    = (const float*)d_in[0];
    const int*   ei   = (const int*)d_in[1];
    const float* W    = (const float*)d_in[2];
    const float* bias = (const float*)d_in[3];
    float* out = (float*)d_out;

    const int n = in_sizes[0] / C;   // 50000
    const int e = in_sizes[1] / 2;   // 800000

    const int npad = (n + 63) & ~63;
    float* deg = (float*)d_ws;
    float* dis = deg + npad;
    float* xt  = dis + npad;         // n*C floats

    fill_deg<<<(n + 255) / 256, 256, 0, stream>>>(deg, n);
    scatter_deg<<<(e + 255) / 256, 256, 0, stream>>>(ei, deg, e);
    rsqrt_deg<<<(n + 255) / 256, 256, 0, stream>>>(deg, dis, n);
    gemm_xw<<<(n + 7) / 8, C, 0, stream>>>(x, W, xt, n);
    out_init<<<(n * C + 255) / 256, 256, 0, stream>>>(xt, dis, bias, out, n);
    long long work = (long long)e * 32;
    edge_scatter<<<(int)((work + 255) / 256), 256, 0, stream>>>(ei, xt, dis, out, e);
}

// Round 2
// 330.807 us; speedup vs baseline: 4.7149x; 4.7149x over previous
//
#include <hip/hip_runtime.h>

#define C 128
#define SCAN_B 256

__global__ void zero_cnt(int* cnt, int n) {
    int i = blockIdx.x * blockDim.x + threadIdx.x;
    if (i < n) cnt[i] = 0;
}

__global__ void hist_dst(const int* __restrict__ ei, int* cnt, int e) {
    int i = blockIdx.x * blockDim.x + threadIdx.x;
    if (i < e) atomicAdd(&cnt[ei[e + i]], 1);
}

__global__ void dis_kernel(const int* __restrict__ cnt, float* dis, int n) {
    int i = blockIdx.x * blockDim.x + threadIdx.x;
    if (i < n) dis[i] = rsqrtf((float)(cnt[i] + 1));  // +1 self-loop
}

// Block-wise exclusive scan of cnt -> row_ptr (partial), block sums -> bsum
__global__ void scan1(const int* __restrict__ cnt, int* row_ptr, int* bsum, int n) {
    __shared__ int s[SCAN_B];
    int t = threadIdx.x;
    int i = blockIdx.x * SCAN_B + t;
    int v = (i < n) ? cnt[i] : 0;
    s[t] = v;
    __syncthreads();
    for (int off = 1; off < SCAN_B; off <<= 1) {
        int u = (t >= off) ? s[t - off] : 0;
        __syncthreads();
        s[t] += u;
        __syncthreads();
    }
    if (i < n) row_ptr[i] = s[t] - v;           // exclusive, block-local
    if (t == SCAN_B - 1) bsum[blockIdx.x] = s[t];
}

// Single-block exclusive scan of block sums (nb <= SCAN_B)
__global__ void scan2(int* bsum, int nb) {
    __shared__ int s[SCAN_B];
    int t = threadIdx.x;
    int v = (t < nb) ? bsum[t] : 0;
    s[t] = v;
    __syncthreads();
    for (int off = 1; off < SCAN_B; off <<= 1) {
        int u = (t >= off) ? s[t - off] : 0;
        __syncthreads();
        s[t] += u;
        __syncthreads();
    }
    if (t < nb) bsum[t] = s[t] - v;             // exclusive
}

// Add block offsets; produce final row_ptr and a cursor copy for reorder.
__global__ void scan3(int* row_ptr, int* cursor, const int* __restrict__ bsum,
                      int n, int e) {
    int i = blockIdx.x * blockDim.x + threadIdx.x;
    if (i < n) {
        int v = row_ptr[i] + bsum[i >> 8];
        row_ptr[i] = v;
        cursor[i] = v;
    }
    if (i == 0) row_ptr[n] = e;
}

// Counting-sort edges by dst: srcs[pos] = src
__global__ void reorder(const int* __restrict__ ei, int* cursor,
                        int* __restrict__ srcs, int e) {
    int i = blockIdx.x * blockDim.x + threadIdx.x;
    if (i < e) {
        int src = ei[i];
        int dst = ei[e + i];
        int pos = atomicAdd(&cursor[dst], 1);
        srcs[pos] = src;
    }
}

// xt = x @ W  (f32 vector ALU; 8-row register tile, LDS-staged W)
__global__ void gemm_xw(const float* __restrict__ x, const float* __restrict__ W,
                        float* __restrict__ xt, int n) {
    __shared__ float Wt[64 * C];
    __shared__ float xs[8 * 64];
    const int c = threadIdx.x;
    int r0 = blockIdx.x * 8;
    if (r0 >= n) return;
    float acc[8];
#pragma unroll
    for (int r = 0; r < 8; ++r) acc[r] = 0.0f;

    for (int kt = 0; kt < 2; ++kt) {
        for (int i = c; i < 64 * C; i += C) Wt[i] = W[kt * 64 * C + i];
        for (int i = c; i < 8 * 64; i += C) {
            int r = i >> 6, k = i & 63;
            int gr = r0 + r;
            xs[i] = (gr < n) ? x[gr * C + kt * 64 + k] : 0.0f;
        }
        __syncthreads();
#pragma unroll 8
        for (int k = 0; k < 64; ++k) {
            float wv = Wt[k * C + c];
#pragma unroll
            for (int r = 0; r < 8; ++r) acc[r] += xs[r * 64 + k] * wv;
        }
        __syncthreads();
    }
#pragma unroll
    for (int r = 0; r < 8; ++r) {
        int gr = r0 + r;
        if (gr < n) xt[gr * C + c] = acc[r];
    }
}

// One 32-lane group per dst node: sum incoming messages + self-loop + bias,
// single float4 store per output element. No atomics.
__global__ void gather(const int* __restrict__ row_ptr, const int* __restrict__ srcs,
                       const float* __restrict__ xt, const float* __restrict__ dis,
                       const float* __restrict__ bias, float* __restrict__ out, int n) {
    int node = blockIdx.x * 8 + (threadIdx.x >> 5);
    int q = threadIdx.x & 31;
    if (node >= n) return;
    const float4* xt4 = (const float4*)xt;
    float d = dis[node];
    int start = row_ptr[node];
    int end = row_ptr[node + 1];
    // self-loop: norm = d*d
    float4 v = xt4[node * 32 + q];
    float ws = d * d;
    float4 acc;
    acc.x = v.x * ws; acc.y = v.y * ws; acc.z = v.z * ws; acc.w = v.w * ws;
    for (int j = start; j < end; ++j) {
        int s = srcs[j];                 // uniform across the 32-lane group
        float w = dis[s] * d;
        float4 m = xt4[s * 32 + q];
        acc.x += m.x * w; acc.y += m.y * w; acc.z += m.z * w; acc.w += m.w * w;
    }
    const float4 b = ((const float4*)bias)[q];
    acc.x += b.x; acc.y += b.y; acc.z += b.z; acc.w += b.w;
    ((float4*)out)[node * 32 + q] = acc;
}

extern "C" void kernel_launch(void* const* d_in, const int* in_sizes, int n_in,
                              void* d_out, int out_size, void* d_ws, size_t ws_size,
                              hipStream_t stream) {
    const float* x    = (const float*)d_in[0];
    const int*   ei   = (const int*)d_in[1];
    const float* W    = (const float*)d_in[2];
    const float* bias = (const float*)d_in[3];
    float* out = (float*)d_out;

    const int n = in_sizes[0] / C;   // 50000
    const int e = in_sizes[1] / 2;   // 800000
    const int nb = (n + SCAN_B - 1) / SCAN_B;  // 196

    // ws layout (4-byte units)
    int*   cnt     = (int*)d_ws;
    int*   cursor  = cnt + n;
    int*   row_ptr = cursor + n;            // n+1
    int*   bsum    = row_ptr + (n + 1);     // nb (pad to 256)
    float* dis     = (float*)(bsum + SCAN_B);
    int*   srcs    = (int*)(dis + n);
    float* xt      = (float*)(srcs + e);

    zero_cnt<<<(n + 255) / 256, 256, 0, stream>>>(cnt, n);
    hist_dst<<<(e + 255) / 256, 256, 0, stream>>>(ei, cnt, e);
    dis_kernel<<<(n + 255) / 256, 256, 0, stream>>>(cnt, dis, n);
    scan1<<<nb, SCAN_B, 0, stream>>>(cnt, row_ptr, bsum, n);
    scan2<<<1, SCAN_B, 0, stream>>>(bsum, nb);
    scan3<<<(n + 255) / 256, 256, 0, stream>>>(row_ptr, cursor, bsum, n, e);
    reorder<<<(e + 255) / 256, 256, 0, stream>>>(ei, cursor, srcs, e);
    gemm_xw<<<(n + 7) / 8, C, 0, stream>>>(x, W, xt, n);
    gather<<<(n + 7) / 8, 256, 0, stream>>>(row_ptr, srcs, xt, dis, bias, out, n);
}

// Round 3
// 274.715 us; speedup vs baseline: 5.6776x; 1.2042x over previous
//
#include <hip/hip_runtime.h>

#define C 128
#define SCAN_B 256

__global__ void zero_cnt(int* cnt, int n) {
    int i = blockIdx.x * blockDim.x + threadIdx.x;
    if (i < n) cnt[i] = 0;
}

__global__ void hist_dst(const int* __restrict__ ei, int* cnt, int e) {
    int i = blockIdx.x * blockDim.x + threadIdx.x;
    if (i < e) atomicAdd(&cnt[ei[e + i]], 1);
}

__global__ void dis_kernel(const int* __restrict__ cnt, float* dis, int n) {
    int i = blockIdx.x * blockDim.x + threadIdx.x;
    if (i < n) dis[i] = rsqrtf((float)(cnt[i] + 1));  // +1 self-loop
}

__global__ void scan1(const int* __restrict__ cnt, int* row_ptr, int* bsum, int n) {
    __shared__ int s[SCAN_B];
    int t = threadIdx.x;
    int i = blockIdx.x * SCAN_B + t;
    int v = (i < n) ? cnt[i] : 0;
    s[t] = v;
    __syncthreads();
    for (int off = 1; off < SCAN_B; off <<= 1) {
        int u = (t >= off) ? s[t - off] : 0;
        __syncthreads();
        s[t] += u;
        __syncthreads();
    }
    if (i < n) row_ptr[i] = s[t] - v;
    if (t == SCAN_B - 1) bsum[blockIdx.x] = s[t];
}

__global__ void scan2(int* bsum, int nb) {
    __shared__ int s[SCAN_B];
    int t = threadIdx.x;
    int v = (t < nb) ? bsum[t] : 0;
    s[t] = v;
    __syncthreads();
    for (int off = 1; off < SCAN_B; off <<= 1) {
        int u = (t >= off) ? s[t - off] : 0;
        __syncthreads();
        s[t] += u;
        __syncthreads();
    }
    if (t < nb) bsum[t] = s[t] - v;
}

__global__ void scan3(int* row_ptr, int* cursor, const int* __restrict__ bsum,
                      int n, int e) {
    int i = blockIdx.x * blockDim.x + threadIdx.x;
    if (i < n) {
        int v = row_ptr[i] + bsum[i >> 8];
        row_ptr[i] = v;
        cursor[i] = v;
    }
    if (i == 0) row_ptr[n] = e;
}

__global__ void reorder(const int* __restrict__ ei, int* cursor,
                        int* __restrict__ srcs, int e) {
    int i = blockIdx.x * blockDim.x + threadIdx.x;
    if (i < e) {
        int src = ei[i];
        int dst = ei[e + i];
        int pos = atomicAdd(&cursor[dst], 1);
        srcs[pos] = src;
    }
}

// xts = (x @ W) * dis[row]   -- register-tiled f32 GEMM
// block: 256 threads, 64 rows x 128 cols; thread tile: 8 rows x 4 cols.
__global__ __launch_bounds__(256) void gemm_xw2(
        const float* __restrict__ x, const float* __restrict__ W,
        const float* __restrict__ dis, float* __restrict__ xts, int n) {
    __shared__ float Ws[16 * 128];    // 8 KB  [kk][c]
    __shared__ float xs[16 * 68];     // 4.25 KB [kk][row], pad 68 -> b128-aligned, <=2-way banks
    const int t = threadIdx.x;
    const int tx = t & 31;            // col group: cols tx*4..tx*4+3
    const int ty = t >> 5;            // row group: rows ty*8..ty*8+7
    const int r0 = blockIdx.x * 64;

    float acc[8][4];
#pragma unroll
    for (int r = 0; r < 8; ++r)
#pragma unroll
        for (int c4 = 0; c4 < 4; ++c4) acc[r][c4] = 0.0f;

    for (int kt = 0; kt < 8; ++kt) {
        const int kbase = kt * 16;
#pragma unroll
        for (int i = 0; i < 8; ++i) {           // W tile: 2048 floats
            int idx = t + i * 256;
            int kk = idx >> 7, c = idx & 127;
            Ws[kk * 128 + c] = W[(kbase + kk) * 128 + c];
        }
#pragma unroll
        for (int i = 0; i < 4; ++i) {           // x tile: 1024 floats
            int idx = t + i * 256;
            int row = idx >> 4, kk = idx & 15;
            int gr = r0 + row;
            xs[kk * 68 + row] = (gr < n) ? x[gr * 128 + kbase + kk] : 0.0f;
        }
        __syncthreads();
#pragma unroll
        for (int kk = 0; kk < 16; ++kk) {
            const float4 wv = *(const float4*)&Ws[kk * 128 + tx * 4];
            const float4 xa = *(const float4*)&xs[kk * 68 + ty * 8];
            const float4 xb = *(const float4*)&xs[kk * 68 + ty * 8 + 4];
            float xr[8] = {xa.x, xa.y, xa.z, xa.w, xb.x, xb.y, xb.z, xb.w};
#pragma unroll
            for (int r = 0; r < 8; ++r) {
                acc[r][0] += xr[r] * wv.x;
                acc[r][1] += xr[r] * wv.y;
                acc[r][2] += xr[r] * wv.z;
                acc[r][3] += xr[r] * wv.w;
            }
        }
        __syncthreads();
    }
#pragma unroll
    for (int r = 0; r < 8; ++r) {
        int gr = r0 + ty * 8 + r;
        if (gr < n) {
            float dv = dis[gr];
            float4 o = make_float4(acc[r][0] * dv, acc[r][1] * dv,
                                   acc[r][2] * dv, acc[r][3] * dv);
            *(float4*)&xts[gr * 128 + tx * 4] = o;
        }
    }
}

// out[i] = dis[i] * (xts[i] + sum_{edges into i} xts[src]) + bias
// 32 lanes per node, float4/lane, x4 unroll with dual accumulators for MLP.
__global__ void gather2(const int* __restrict__ row_ptr, const int* __restrict__ srcs,
                        const float* __restrict__ xts, const float* __restrict__ dis,
                        const float* __restrict__ bias, float* __restrict__ out, int n) {
    int node = blockIdx.x * 8 + (threadIdx.x >> 5);
    int q = threadIdx.x & 31;
    if (node >= n) return;
    const float4* x4 = (const float4*)xts;
    int start = row_ptr[node];
    int end = row_ptr[node + 1];
    float4 a0 = x4[node * 32 + q];   // self-loop (xts already has dis folded)
    float4 a1 = make_float4(0.f, 0.f, 0.f, 0.f);
    int j = start;
    for (; j + 4 <= end; j += 4) {
        int s0 = srcs[j], s1 = srcs[j + 1], s2 = srcs[j + 2], s3 = srcs[j + 3];
        float4 m0 = x4[s0 * 32 + q];
        float4 m1 = x4[s1 * 32 + q];
        float4 m2 = x4[s2 * 32 + q];
        float4 m3 = x4[s3 * 32 + q];
        a0.x += m0.x; a0.y += m0.y; a0.z += m0.z; a0.w += m0.w;
        a1.x += m1.x; a1.y += m1.y; a1.z += m1.z; a1.w += m1.w;
        a0.x += m2.x; a0.y += m2.y; a0.z += m2.z; a0.w += m2.w;
        a1.x += m3.x; a1.y += m3.y; a1.z += m3.z; a1.w += m3.w;
    }
    for (; j < end; ++j) {
        int s = srcs[j];
        float4 m = x4[s * 32 + q];
        a0.x += m.x; a0.y += m.y; a0.z += m.z; a0.w += m.w;
    }
    float d = dis[node];
    float4 b = ((const float4*)bias)[q];
    float4 o;
    o.x = (a0.x + a1.x) * d + b.x;
    o.y = (a0.y + a1.y) * d + b.y;
    o.z = (a0.z + a1.z) * d + b.z;
    o.w = (a0.w + a1.w) * d + b.w;
    ((float4*)out)[node * 32 + q] = o;
}

extern "C" void kernel_launch(void* const* d_in, const int* in_sizes, int n_in,
                              void* d_out, int out_size, void* d_ws, size_t ws_size,
                              hipStream_t stream) {
    const float* x    = (const float*)d_in[0];
    const int*   ei   = (const int*)d_in[1];
    const float* W    = (const float*)d_in[2];
    const float* bias = (const float*)d_in[3];
    float* out = (float*)d_out;

    const int n = in_sizes[0] / C;   // 50000
    const int e = in_sizes[1] / 2;   // 800000
    const int nb = (n + SCAN_B - 1) / SCAN_B;

    int*   cnt     = (int*)d_ws;
    int*   cursor  = cnt + n;
    int*   row_ptr = cursor + n;            // n+1
    int*   bsum    = row_ptr + (n + 1);     // nb (pad to 256)
    float* dis     = (float*)(bsum + SCAN_B);
    int*   srcs    = (int*)(dis + n);
    float* xts     = (float*)(srcs + e);

    zero_cnt<<<(n + 255) / 256, 256, 0, stream>>>(cnt, n);
    hist_dst<<<(e + 255) / 256, 256, 0, stream>>>(ei, cnt, e);
    dis_kernel<<<(n + 255) / 256, 256, 0, stream>>>(cnt, dis, n);
    scan1<<<nb, SCAN_B, 0, stream>>>(cnt, row_ptr, bsum, n);
    scan2<<<1, SCAN_B, 0, stream>>>(bsum, nb);
    scan3<<<(n + 255) / 256, 256, 0, stream>>>(row_ptr, cursor, bsum, n, e);
    reorder<<<(e + 255) / 256, 256, 0, stream>>>(ei, cursor, srcs, e);
    gemm_xw2<<<(n + 63) / 64, 256, 0, stream>>>(x, W, dis, xts, n);
    gather2<<<(n + 7) / 8, 256, 0, stream>>>(row_ptr, srcs, xts, dis, bias, out, n);
}

// Round 4
// 250.663 us; speedup vs baseline: 6.2224x; 1.0960x over previous
//
#include <hip/hip_runtime.h>

#define C 128
#define SCAN_B 256

__device__ inline unsigned short f2bf(float f) {   // RNE f32 -> bf16
    unsigned u = __float_as_uint(f);
    u += 0x7fffu + ((u >> 16) & 1u);
    return (unsigned short)(u >> 16);
}

__global__ void hist_dst(const int* __restrict__ ei, int* cnt, int e) {
    int i = blockIdx.x * blockDim.x + threadIdx.x;
    if (i < e) atomicAdd(&cnt[ei[e + i]], 1);
}

// block-local exclusive scan of cnt -> row_ptr, block sums -> bsum, dis fused
__global__ void scan1(const int* __restrict__ cnt, int* row_ptr, int* bsum,
                      float* dis, int n) {
    __shared__ int s[SCAN_B];
    int t = threadIdx.x;
    int i = blockIdx.x * SCAN_B + t;
    int v = (i < n) ? cnt[i] : 0;
    if (i < n) dis[i] = rsqrtf((float)(v + 1));   // +1 self-loop
    s[t] = v;
    __syncthreads();
    for (int off = 1; off < SCAN_B; off <<= 1) {
        int u = (t >= off) ? s[t - off] : 0;
        __syncthreads();
        s[t] += u;
        __syncthreads();
    }
    if (i < n) row_ptr[i] = s[t] - v;
    if (t == SCAN_B - 1) bsum[blockIdx.x] = s[t];
}

// fused scan2+scan3: every block scans the nb block-sums redundantly in LDS
__global__ void scan23(int* row_ptr, int* cursor, const int* __restrict__ bsum,
                       int n, int e, int nb) {
    __shared__ int s[SCAN_B];
    int t = threadIdx.x;
    int v = (t < nb) ? bsum[t] : 0;
    s[t] = v;
    __syncthreads();
    for (int off = 1; off < SCAN_B; off <<= 1) {
        int u = (t >= off) ? s[t - off] : 0;
        __syncthreads();
        s[t] += u;
        __syncthreads();
    }
    int p = (blockIdx.x > 0) ? s[blockIdx.x - 1] : 0;  // exclusive prefix of this block
    int i = blockIdx.x * SCAN_B + t;
    if (i < n) {
        int v2 = row_ptr[i] + p;
        row_ptr[i] = v2;
        cursor[i] = v2;
    }
    if (blockIdx.x == 0 && t == 0) row_ptr[n] = e;
}

__global__ void reorder(const int* __restrict__ ei, int* cursor,
                        int* __restrict__ srcs, int e) {
    int i = blockIdx.x * blockDim.x + threadIdx.x;
    if (i < e) {
        int src = ei[i];
        int dst = ei[e + i];
        int pos = atomicAdd(&cursor[dst], 1);
        srcs[pos] = src;
    }
}

// xts(bf16) = (x @ W) * dis[row]  -- register-tiled f32 GEMM, bf16 epilogue
__global__ __launch_bounds__(256) void gemm_xw2(
        const float* __restrict__ x, const float* __restrict__ W,
        const float* __restrict__ dis, unsigned short* __restrict__ xts, int n) {
    __shared__ float Ws[16 * 128];
    __shared__ float xs[16 * 68];
    const int t = threadIdx.x;
    const int tx = t & 31;
    const int ty = t >> 5;
    const int r0 = blockIdx.x * 64;

    float acc[8][4];
#pragma unroll
    for (int r = 0; r < 8; ++r)
#pragma unroll
        for (int c4 = 0; c4 < 4; ++c4) acc[r][c4] = 0.0f;

    for (int kt = 0; kt < 8; ++kt) {
        const int kbase = kt * 16;
#pragma unroll
        for (int i = 0; i < 8; ++i) {
            int idx = t + i * 256;
            int kk = idx >> 7, c = idx & 127;
            Ws[kk * 128 + c] = W[(kbase + kk) * 128 + c];
        }
#pragma unroll
        for (int i = 0; i < 4; ++i) {
            int idx = t + i * 256;
            int row = idx >> 4, kk = idx & 15;
            int gr = r0 + row;
            xs[kk * 68 + row] = (gr < n) ? x[gr * 128 + kbase + kk] : 0.0f;
        }
        __syncthreads();
#pragma unroll
        for (int kk = 0; kk < 16; ++kk) {
            const float4 wv = *(const float4*)&Ws[kk * 128 + tx * 4];
            const float4 xa = *(const float4*)&xs[kk * 68 + ty * 8];
            const float4 xb = *(const float4*)&xs[kk * 68 + ty * 8 + 4];
            float xr[8] = {xa.x, xa.y, xa.z, xa.w, xb.x, xb.y, xb.z, xb.w};
#pragma unroll
            for (int r = 0; r < 8; ++r) {
                acc[r][0] += xr[r] * wv.x;
                acc[r][1] += xr[r] * wv.y;
                acc[r][2] += xr[r] * wv.z;
                acc[r][3] += xr[r] * wv.w;
            }
        }
        __syncthreads();
    }
#pragma unroll
    for (int r = 0; r < 8; ++r) {
        int gr = r0 + ty * 8 + r;
        if (gr < n) {
            float dv = dis[gr];
            ushort4 o;
            o.x = f2bf(acc[r][0] * dv);
            o.y = f2bf(acc[r][1] * dv);
            o.z = f2bf(acc[r][2] * dv);
            o.w = f2bf(acc[r][3] * dv);
            *(ushort4*)&xts[gr * 128 + tx * 4] = o;
        }
    }
}

__device__ inline void acc8(float* a, uint4 w) {
    a[0] += __uint_as_float(w.x << 16);
    a[1] += __uint_as_float(w.x & 0xffff0000u);
    a[2] += __uint_as_float(w.y << 16);
    a[3] += __uint_as_float(w.y & 0xffff0000u);
    a[4] += __uint_as_float(w.z << 16);
    a[5] += __uint_as_float(w.z & 0xffff0000u);
    a[6] += __uint_as_float(w.w << 16);
    a[7] += __uint_as_float(w.w & 0xffff0000u);
}

// out[i] = dis[i]*(xts[i] + sum_in xts[src]) + bias ; 16 lanes/node, 16B/lane bf16
__global__ void gather3(const int* __restrict__ row_ptr, const int* __restrict__ srcs,
                        const unsigned short* __restrict__ xts,
                        const float* __restrict__ dis,
                        const float* __restrict__ bias, float* __restrict__ out, int n) {
    int node = blockIdx.x * 16 + (threadIdx.x >> 4);
    int q = threadIdx.x & 15;
    if (node >= n) return;
    const uint4* x4 = (const uint4*)xts;   // row = 16 uint4 (256 B)
    int start = row_ptr[node];
    int end = row_ptr[node + 1];
    float a0[8] = {0, 0, 0, 0, 0, 0, 0, 0};
    float a1[8] = {0, 0, 0, 0, 0, 0, 0, 0};
    acc8(a0, x4[node * 16 + q]);           // self-loop (dis already folded)
    int j = start;
    for (; j + 4 <= end; j += 4) {
        uint4 m0 = x4[srcs[j] * 16 + q];
        uint4 m1 = x4[srcs[j + 1] * 16 + q];
        uint4 m2 = x4[srcs[j + 2] * 16 + q];
        uint4 m3 = x4[srcs[j + 3] * 16 + q];
        acc8(a0, m0);
        acc8(a1, m1);
        acc8(a0, m2);
        acc8(a1, m3);
    }
    for (; j < end; ++j) acc8(a0, x4[srcs[j] * 16 + q]);
    float d = dis[node];
    const float4 b0 = ((const float4*)bias)[q * 2];
    const float4 b1 = ((const float4*)bias)[q * 2 + 1];
    float4 o0, o1;
    o0.x = (a0[0] + a1[0]) * d + b0.x;
    o0.y = (a0[1] + a1[1]) * d + b0.y;
    o0.z = (a0[2] + a1[2]) * d + b0.z;
    o0.w = (a0[3] + a1[3]) * d + b0.w;
    o1.x = (a0[4] + a1[4]) * d + b1.x;
    o1.y = (a0[5] + a1[5]) * d + b1.y;
    o1.z = (a0[6] + a1[6]) * d + b1.z;
    o1.w = (a0[7] + a1[7]) * d + b1.w;
    float4* op = (float4*)(out + node * 128 + q * 8);
    op[0] = o0;
    op[1] = o1;
}

extern "C" void kernel_launch(void* const* d_in, const int* in_sizes, int n_in,
                              void* d_out, int out_size, void* d_ws, size_t ws_size,
                              hipStream_t stream) {
    const float* x    = (const float*)d_in[0];
    const int*   ei   = (const int*)d_in[1];
    const float* W    = (const float*)d_in[2];
    const float* bias = (const float*)d_in[3];
    float* out = (float*)d_out;

    const int n = in_sizes[0] / C;   // 50000
    const int e = in_sizes[1] / 2;   // 800000
    const int nb = (n + SCAN_B - 1) / SCAN_B;

    // ws layout, 16B-aligned chunks
    char* p = (char*)d_ws;
    auto alloc = [&](size_t bytes) {
        char* r = p;
        p += (bytes + 15) & ~(size_t)15;
        return (void*)r;
    };
    int*   cnt     = (int*)alloc(n * 4);
    int*   cursor  = (int*)alloc(n * 4);
    int*   row_ptr = (int*)alloc((n + 1) * 4);
    int*   bsum    = (int*)alloc(SCAN_B * 4);
    float* dis     = (float*)alloc(n * 4);
    int*   srcs    = (int*)alloc((size_t)e * 4);
    unsigned short* xts = (unsigned short*)alloc((size_t)n * C * 2);

    hipMemsetAsync(cnt, 0, n * 4, stream);
    hist_dst<<<(e + 255) / 256, 256, 0, stream>>>(ei, cnt, e);
    scan1<<<nb, SCAN_B, 0, stream>>>(cnt, row_ptr, bsum, dis, n);
    scan23<<<nb, SCAN_B, 0, stream>>>(row_ptr, cursor, bsum, n, e, nb);
    reorder<<<(e + 255) / 256, 256, 0, stream>>>(ei, cursor, srcs, e);
    gemm_xw2<<<(n + 63) / 64, 256, 0, stream>>>(x, W, dis, xts, n);
    gather3<<<(n + 15) / 16, 256, 0, stream>>>(row_ptr, srcs, xts, dis, bias, out, n);
}

// Round 5
// 242.121 us; speedup vs baseline: 6.4419x; 1.0353x over previous
//
#include <hip/hip_runtime.h>

#define C 128
#define SCAN_B 256

typedef short bf16x8 __attribute__((ext_vector_type(8)));
typedef float f32x4 __attribute__((ext_vector_type(4)));

__device__ inline unsigned short f2bf(float f) {   // RNE f32 -> bf16
    unsigned u = __float_as_uint(f);
    u += 0x7fffu + ((u >> 16) & 1u);
    return (unsigned short)(u >> 16);
}

__device__ inline unsigned pk2bf(float lo, float hi) {
    return (unsigned)f2bf(lo) | ((unsigned)f2bf(hi) << 16);
}

__global__ void hist_dst(const int* __restrict__ ei, int* cnt, int e) {
    int i = blockIdx.x * blockDim.x + threadIdx.x;
    if (i < e) atomicAdd(&cnt[ei[e + i]], 1);
}

// Wt[n][k] = bf16(W[k][n])   (32 KB, one-time)
__global__ void wcvt(const float* __restrict__ W, unsigned short* __restrict__ Wt) {
    int i = blockIdx.x * blockDim.x + threadIdx.x;   // 16384
    int nn = i >> 7, k = i & 127;
    Wt[nn * 128 + k] = f2bf(W[k * 128 + nn]);
}

// block-local exclusive scan of cnt -> row_ptr, block sums -> bsum, dis fused
__global__ void scan1(const int* __restrict__ cnt, int* row_ptr, int* bsum,
                      float* dis, int n) {
    __shared__ int s[SCAN_B];
    int t = threadIdx.x;
    int i = blockIdx.x * SCAN_B + t;
    int v = (i < n) ? cnt[i] : 0;
    if (i < n) dis[i] = rsqrtf((float)(v + 1));   // +1 self-loop
    s[t] = v;
    __syncthreads();
    for (int off = 1; off < SCAN_B; off <<= 1) {
        int u = (t >= off) ? s[t - off] : 0;
        __syncthreads();
        s[t] += u;
        __syncthreads();
    }
    if (i < n) row_ptr[i] = s[t] - v;
    if (t == SCAN_B - 1) bsum[blockIdx.x] = s[t];
}

// fused scan2+scan3
__global__ void scan23(int* row_ptr, int* cursor, const int* __restrict__ bsum,
                       int n, int e, int nb) {
    __shared__ int s[SCAN_B];
    int t = threadIdx.x;
    int v = (t < nb) ? bsum[t] : 0;
    s[t] = v;
    __syncthreads();
    for (int off = 1; off < SCAN_B; off <<= 1) {
        int u = (t >= off) ? s[t - off] : 0;
        __syncthreads();
        s[t] += u;
        __syncthreads();
    }
    int p = (blockIdx.x > 0) ? s[blockIdx.x - 1] : 0;
    int i = blockIdx.x * SCAN_B + t;
    if (i < n) {
        int v2 = row_ptr[i] + p;
        row_ptr[i] = v2;
        cursor[i] = v2;
    }
    if (blockIdx.x == 0 && t == 0) row_ptr[n] = e;
}

__global__ void reorder(const int* __restrict__ ei, int* cursor,
                        int* __restrict__ srcs, int e) {
    int i = blockIdx.x * blockDim.x + threadIdx.x;
    if (i < e) {
        int src = ei[i];
        int dst = ei[e + i];
        int pos = atomicAdd(&cursor[dst], 1);
        __builtin_nontemporal_store(src, &srcs[pos]);
    }
}

// xts(bf16) = (x @ W) * dis[row], MFMA 16x16x32 bf16.
// 256 thr = 4 waves; wave handles 16 rows x 128 cols; LDS-free (Wt is L1/L2-hot).
__global__ __launch_bounds__(256) void gemm_mfma(
        const float* __restrict__ x, const unsigned short* __restrict__ Wt,
        const float* __restrict__ dis, unsigned short* __restrict__ xts, int n) {
    const int lane = threadIdx.x & 63;
    const int wave = threadIdx.x >> 6;
    const int m = lane & 15;          // A row / B col / D col within tile
    const int q = lane >> 4;          // quad 0..3
    const int r0 = blockIdx.x * 64 + wave * 16;
    const int row = r0 + m;
    const int rowc = (row < n) ? row : (n - 1);

    f32x4 acc[8];
#pragma unroll
    for (int nt = 0; nt < 8; ++nt) acc[nt] = (f32x4){0.f, 0.f, 0.f, 0.f};

#pragma unroll
    for (int kb = 0; kb < 4; ++kb) {
        const int k0 = kb * 32 + q * 8;
        const float4* xp = (const float4*)(x + (size_t)rowc * 128 + k0);
        float4 xa = xp[0];
        float4 xb = xp[1];
        union { unsigned u[4]; bf16x8 v; } af;
        af.u[0] = pk2bf(xa.x, xa.y);
        af.u[1] = pk2bf(xa.z, xa.w);
        af.u[2] = pk2bf(xb.x, xb.y);
        af.u[3] = pk2bf(xb.z, xb.w);
#pragma unroll
        for (int nt = 0; nt < 8; ++nt) {
            bf16x8 bf = *(const bf16x8*)(Wt + (size_t)(nt * 16 + m) * 128 + k0);
            acc[nt] = __builtin_amdgcn_mfma_f32_16x16x32_bf16(af.v, bf, acc[nt], 0, 0, 0);
        }
    }

    // C/D: col = nt*16 + (lane&15), row = r0 + q*4 + reg
    float dv[4];
    int gr[4];
#pragma unroll
    for (int r = 0; r < 4; ++r) {
        gr[r] = r0 + q * 4 + r;
        dv[r] = dis[(gr[r] < n) ? gr[r] : (n - 1)];
    }
#pragma unroll
    for (int nt = 0; nt < 8; ++nt) {
        int col = nt * 16 + m;
#pragma unroll
        for (int r = 0; r < 4; ++r) {
            if (gr[r] < n)
                xts[(size_t)gr[r] * 128 + col] = f2bf(acc[nt][r] * dv[r]);
        }
    }
}

__device__ inline void acc8(float* a, uint4 w) {
    a[0] += __uint_as_float(w.x << 16);
    a[1] += __uint_as_float(w.x & 0xffff0000u);
    a[2] += __uint_as_float(w.y << 16);
    a[3] += __uint_as_float(w.y & 0xffff0000u);
    a[4] += __uint_as_float(w.z << 16);
    a[5] += __uint_as_float(w.z & 0xffff0000u);
    a[6] += __uint_as_float(w.w << 16);
    a[7] += __uint_as_float(w.w & 0xffff0000u);
}

// out[i] = dis[i]*(xts[i] + sum_in xts[src]) + bias ; 16 lanes/node, 16B/lane bf16
__global__ void gather3(const int* __restrict__ row_ptr, const int* __restrict__ srcs,
                        const unsigned short* __restrict__ xts,
                        const float* __restrict__ dis,
                        const float* __restrict__ bias, float* __restrict__ out, int n) {
    int node = blockIdx.x * 16 + (threadIdx.x >> 4);
    int q = threadIdx.x & 15;
    if (node >= n) return;
    const uint4* x4 = (const uint4*)xts;   // row = 16 uint4 (256 B)
    int start = row_ptr[node];
    int end = row_ptr[node + 1];
    float a0[8] = {0, 0, 0, 0, 0, 0, 0, 0};
    float a1[8] = {0, 0, 0, 0, 0, 0, 0, 0};
    acc8(a0, x4[node * 16 + q]);           // self-loop (dis already folded)
    int j = start;
    for (; j + 4 <= end; j += 4) {
        uint4 m0 = x4[srcs[j] * 16 + q];
        uint4 m1 = x4[srcs[j + 1] * 16 + q];
        uint4 m2 = x4[srcs[j + 2] * 16 + q];
        uint4 m3 = x4[srcs[j + 3] * 16 + q];
        acc8(a0, m0);
        acc8(a1, m1);
        acc8(a0, m2);
        acc8(a1, m3);
    }
    for (; j < end; ++j) acc8(a0, x4[srcs[j] * 16 + q]);
    float d = dis[node];
    const float4 b0 = ((const float4*)bias)[q * 2];
    const float4 b1 = ((const float4*)bias)[q * 2 + 1];
    float4 o0, o1;
    o0.x = (a0[0] + a1[0]) * d + b0.x;
    o0.y = (a0[1] + a1[1]) * d + b0.y;
    o0.z = (a0[2] + a1[2]) * d + b0.z;
    o0.w = (a0[3] + a1[3]) * d + b0.w;
    o1.x = (a0[4] + a1[4]) * d + b1.x;
    o1.y = (a0[5] + a1[5]) * d + b1.y;
    o1.z = (a0[6] + a1[6]) * d + b1.z;
    o1.w = (a0[7] + a1[7]) * d + b1.w;
    float4* op = (float4*)(out + node * 128 + q * 8);
    op[0] = o0;
    op[1] = o1;
}

extern "C" void kernel_launch(void* const* d_in, const int* in_sizes, int n_in,
                              void* d_out, int out_size, void* d_ws, size_t ws_size,
                              hipStream_t stream) {
    const float* x    = (const float*)d_in[0];
    const int*   ei   = (const int*)d_in[1];
    const float* W    = (const float*)d_in[2];
    const float* bias = (const float*)d_in[3];
    float* out = (float*)d_out;

    const int n = in_sizes[0] / C;   // 50000
    const int e = in_sizes[1] / 2;   // 800000
    const int nb = (n + SCAN_B - 1) / SCAN_B;

    char* p = (char*)d_ws;
    auto alloc = [&](size_t bytes) {
        char* r = p;
        p += (bytes + 15) & ~(size_t)15;
        return (void*)r;
    };
    int*   cnt     = (int*)alloc(n * 4);
    int*   cursor  = (int*)alloc(n * 4);
    int*   row_ptr = (int*)alloc((n + 1) * 4);
    int*   bsum    = (int*)alloc(SCAN_B * 4);
    float* dis     = (float*)alloc(n * 4);
    int*   srcs    = (int*)alloc((size_t)e * 4);
    unsigned short* xts = (unsigned short*)alloc((size_t)n * C * 2);
    unsigned short* Wt  = (unsigned short*)alloc(128 * 128 * 2);

    hipMemsetAsync(cnt, 0, n * 4, stream);
    wcvt<<<64, 256, 0, stream>>>(W, Wt);
    hist_dst<<<(e + 255) / 256, 256, 0, stream>>>(ei, cnt, e);
    scan1<<<nb, SCAN_B, 0, stream>>>(cnt, row_ptr, bsum, dis, n);
    scan23<<<nb, SCAN_B, 0, stream>>>(row_ptr, cursor, bsum, n, e, nb);
    reorder<<<(e + 255) / 256, 256, 0, stream>>>(ei, cursor, srcs, e);
    gemm_mfma<<<(n + 63) / 64, 256, 0, stream>>>(x, Wt, dis, xts, n);
    gather3<<<(n + 15) / 16, 256, 0, stream>>>(row_ptr, srcs, xts, dis, bias, out, n);
}

// Round 6
// 229.070 us; speedup vs baseline: 6.8089x; 1.0570x over previous
//
#include <hip/hip_runtime.h>

#define C 128
#define CHUNK 4096   // edges per K1/K3 block

typedef short bf16x8 __attribute__((ext_vector_type(8)));
typedef float f32x4 __attribute__((ext_vector_type(4)));

__device__ inline unsigned short f2bf(float f) {   // RNE f32 -> bf16
    unsigned u = __float_as_uint(f);
    u += 0x7fffu + ((u >> 16) & 1u);
    return (unsigned short)(u >> 16);
}

__device__ inline unsigned pk2bf(float lo, float hi) {
    return (unsigned)f2bf(lo) | ((unsigned)f2bf(hi) << 16);
}

// K1: per-chunk LDS histogram of dst>>8 -> H[bucket][block]; wcvt fused as
// trailing blocks (Wt[n][k] = bf16(W[k][n])).
__global__ __launch_bounds__(256) void k1_hist(
        const int* __restrict__ ei, int e, int* __restrict__ H,
        int nblocks, int nbuck,
        const float* __restrict__ W, unsigned short* __restrict__ Wt) {
    int b = blockIdx.x;
    int t = threadIdx.x;
    if (b >= nblocks) {   // wcvt: 64 blocks x 256 = 16384 elements
        int i = (b - nblocks) * 256 + t;
        int nn = i >> 7, k = i & 127;
        Wt[nn * 128 + k] = f2bf(W[k * 128 + nn]);
        return;
    }
    __shared__ int h[256];
    h[t] = 0;
    __syncthreads();
    int base = b * CHUNK;
    int lim = min(CHUNK, e - base);
    for (int i = t; i < lim; i += 256)
        atomicAdd(&h[ei[e + base + i] >> 8], 1);
    __syncthreads();
    if (t < nbuck) H[t * nblocks + b] = h[t];
}

// K2: single block. bucket totals -> exclusive bucket bases (bbase[nbuck]=e);
// rewrite H[bucket][block] into per-(bucket,block) start offsets.
__global__ __launch_bounds__(256) void k2_scan(
        int* __restrict__ H, int* __restrict__ bbase, int nblocks, int nbuck) {
    __shared__ int tot[256];
    int t = threadIdx.x;
    int sum = 0;
    if (t < nbuck)
        for (int b = 0; b < nblocks; ++b) sum += H[t * nblocks + b];
    tot[t] = sum;
    __syncthreads();
    for (int off = 1; off < 256; off <<= 1) {
        int u = (t >= off) ? tot[t - off] : 0;
        __syncthreads();
        tot[t] += u;
        __syncthreads();
    }
    int excl = tot[t] - sum;
    if (t < nbuck) {
        bbase[t] = excl;
        int run = excl;
        for (int b = 0; b < nblocks; ++b) {
            int v = H[t * nblocks + b];
            H[t * nblocks + b] = run;
            run += v;
        }
    }
    if (t == nbuck) bbase[t] = tot[255];   // = e
}

// K3: rank edges by bucket via LDS cursors (no global atomics), write 4B
// records (dstlow:8)<<16 | src to per-block-disjoint contiguous runs.
__global__ __launch_bounds__(256) void k3_scatter(
        const int* __restrict__ ei, int e, const int* __restrict__ H,
        unsigned* __restrict__ staging, int nblocks, int nbuck) {
    __shared__ int cur[256];
    int b = blockIdx.x, t = threadIdx.x;
    if (t < nbuck) cur[t] = H[t * nblocks + b];
    __syncthreads();
    int base = b * CHUNK;
    int lim = min(CHUNK, e - base);
    for (int i = t; i < lim; i += 256) {
        int src = ei[base + i];
        int dst = ei[e + base + i];
        int pos = atomicAdd(&cur[dst >> 8], 1);
        staging[pos] = (unsigned)src | ((unsigned)(dst & 255) << 16);
    }
}

// K4: one block per bucket. LDS-count low bytes -> row_ptr, dis, then scatter
// src (ushort) into the bucket's own contiguous srcs region.
__global__ __launch_bounds__(256) void k4_finalize(
        const unsigned* __restrict__ staging, const int* __restrict__ bbase,
        int* __restrict__ row_ptr, float* __restrict__ dis,
        unsigned short* __restrict__ srcs, int n) {
    __shared__ int sc[256];
    __shared__ int cur[256];
    int g = blockIdx.x, t = threadIdx.x;
    int s0 = bbase[g], s1 = bbase[g + 1];
    sc[t] = 0;
    __syncthreads();
    for (int i = s0 + t; i < s1; i += 256)
        atomicAdd(&sc[staging[i] >> 16], 1);
    __syncthreads();
    int v = sc[t];
    __syncthreads();
    // exclusive scan of counts
    for (int off = 1; off < 256; off <<= 1) {
        int u = (t >= off) ? sc[t - off] : 0;
        __syncthreads();
        sc[t] += u;
        __syncthreads();
    }
    int excl = sc[t] - v;
    int idx = g * 256 + t;
    if (idx <= n) row_ptr[idx] = s0 + excl;    // idx==n lands here for g=last
    if (idx < n) dis[idx] = rsqrtf((float)(v + 1));
    cur[t] = s0 + excl;
    __syncthreads();
    for (int i = s0 + t; i < s1; i += 256) {
        unsigned rec = staging[i];
        int pos = atomicAdd(&cur[rec >> 16], 1);
        srcs[pos] = (unsigned short)(rec & 0xffffu);
    }
}

// xts(bf16) = (x @ W) * dis[row], MFMA 16x16x32 bf16, LDS-free.
__global__ __launch_bounds__(256) void gemm_mfma(
        const float* __restrict__ x, const unsigned short* __restrict__ Wt,
        const float* __restrict__ dis, unsigned short* __restrict__ xts, int n) {
    const int lane = threadIdx.x & 63;
    const int wave = threadIdx.x >> 6;
    const int m = lane & 15;
    const int q = lane >> 4;
    const int r0 = blockIdx.x * 64 + wave * 16;
    const int row = r0 + m;
    const int rowc = (row < n) ? row : (n - 1);

    f32x4 acc[8];
#pragma unroll
    for (int nt = 0; nt < 8; ++nt) acc[nt] = (f32x4){0.f, 0.f, 0.f, 0.f};

#pragma unroll
    for (int kb = 0; kb < 4; ++kb) {
        const int k0 = kb * 32 + q * 8;
        const float4* xp = (const float4*)(x + (size_t)rowc * 128 + k0);
        float4 xa = xp[0];
        float4 xb = xp[1];
        union { unsigned u[4]; bf16x8 v; } af;
        af.u[0] = pk2bf(xa.x, xa.y);
        af.u[1] = pk2bf(xa.z, xa.w);
        af.u[2] = pk2bf(xb.x, xb.y);
        af.u[3] = pk2bf(xb.z, xb.w);
#pragma unroll
        for (int nt = 0; nt < 8; ++nt) {
            bf16x8 bf = *(const bf16x8*)(Wt + (size_t)(nt * 16 + m) * 128 + k0);
            acc[nt] = __builtin_amdgcn_mfma_f32_16x16x32_bf16(af.v, bf, acc[nt], 0, 0, 0);
        }
    }

    float dv[4];
    int gr[4];
#pragma unroll
    for (int r = 0; r < 4; ++r) {
        gr[r] = r0 + q * 4 + r;
        dv[r] = dis[(gr[r] < n) ? gr[r] : (n - 1)];
    }
#pragma unroll
    for (int nt = 0; nt < 8; ++nt) {
        int col = nt * 16 + m;
#pragma unroll
        for (int r = 0; r < 4; ++r) {
            if (gr[r] < n)
                xts[(size_t)gr[r] * 128 + col] = f2bf(acc[nt][r] * dv[r]);
        }
    }
}

__device__ inline void acc8(float* a, uint4 w) {
    a[0] += __uint_as_float(w.x << 16);
    a[1] += __uint_as_float(w.x & 0xffff0000u);
    a[2] += __uint_as_float(w.y << 16);
    a[3] += __uint_as_float(w.y & 0xffff0000u);
    a[4] += __uint_as_float(w.z << 16);
    a[5] += __uint_as_float(w.z & 0xffff0000u);
    a[6] += __uint_as_float(w.w << 16);
    a[7] += __uint_as_float(w.w & 0xffff0000u);
}

// out[i] = dis[i]*(xts[i] + sum_in xts[src]) + bias ; 16 lanes/node
__global__ void gather3(const int* __restrict__ row_ptr,
                        const unsigned short* __restrict__ srcs,
                        const unsigned short* __restrict__ xts,
                        const float* __restrict__ dis,
                        const float* __restrict__ bias, float* __restrict__ out, int n) {
    int node = blockIdx.x * 16 + (threadIdx.x >> 4);
    int q = threadIdx.x & 15;
    if (node >= n) return;
    const uint4* x4 = (const uint4*)xts;
    int start = row_ptr[node];
    int end = row_ptr[node + 1];
    float a0[8] = {0, 0, 0, 0, 0, 0, 0, 0};
    float a1[8] = {0, 0, 0, 0, 0, 0, 0, 0};
    acc8(a0, x4[node * 16 + q]);
    int j = start;
    for (; j + 4 <= end; j += 4) {
        uint4 m0 = x4[(int)srcs[j] * 16 + q];
        uint4 m1 = x4[(int)srcs[j + 1] * 16 + q];
        uint4 m2 = x4[(int)srcs[j + 2] * 16 + q];
        uint4 m3 = x4[(int)srcs[j + 3] * 16 + q];
        acc8(a0, m0);
        acc8(a1, m1);
        acc8(a0, m2);
        acc8(a1, m3);
    }
    for (; j < end; ++j) acc8(a0, x4[(int)srcs[j] * 16 + q]);
    float d = dis[node];
    const float4 b0 = ((const float4*)bias)[q * 2];
    const float4 b1 = ((const float4*)bias)[q * 2 + 1];
    float4 o0, o1;
    o0.x = (a0[0] + a1[0]) * d + b0.x;
    o0.y = (a0[1] + a1[1]) * d + b0.y;
    o0.z = (a0[2] + a1[2]) * d + b0.z;
    o0.w = (a0[3] + a1[3]) * d + b0.w;
    o1.x = (a0[4] + a1[4]) * d + b1.x;
    o1.y = (a0[5] + a1[5]) * d + b1.y;
    o1.z = (a0[6] + a1[6]) * d + b1.z;
    o1.w = (a0[7] + a1[7]) * d + b1.w;
    float4* op = (float4*)(out + node * 128 + q * 8);
    op[0] = o0;
    op[1] = o1;
}

extern "C" void kernel_launch(void* const* d_in, const int* in_sizes, int n_in,
                              void* d_out, int out_size, void* d_ws, size_t ws_size,
                              hipStream_t stream) {
    const float* x    = (const float*)d_in[0];
    const int*   ei   = (const int*)d_in[1];
    const float* W    = (const float*)d_in[2];
    const float* bias = (const float*)d_in[3];
    float* out = (float*)d_out;

    const int n = in_sizes[0] / C;             // 50000  (must be < 65536)
    const int e = in_sizes[1] / 2;             // 800000
    const int nblocks = (e + CHUNK - 1) / CHUNK;  // 196
    const int nbuck = (n + 255) >> 8;             // 196

    char* p = (char*)d_ws;
    auto alloc = [&](size_t bytes) {
        char* r = p;
        p += (bytes + 15) & ~(size_t)15;
        return (void*)r;
    };
    int*      H       = (int*)alloc((size_t)nbuck * nblocks * 4);
    int*      bbase   = (int*)alloc((nbuck + 1) * 4);
    unsigned* staging = (unsigned*)alloc((size_t)e * 4);
    int*      row_ptr = (int*)alloc((n + 1) * 4);
    float*    dis     = (float*)alloc(n * 4);
    unsigned short* srcs = (unsigned short*)alloc((size_t)e * 2);
    unsigned short* xts  = (unsigned short*)alloc((size_t)n * C * 2);
    unsigned short* Wt   = (unsigned short*)alloc(128 * 128 * 2);

    k1_hist<<<nblocks + 64, 256, 0, stream>>>(ei, e, H, nblocks, nbuck, W, Wt);
    k2_scan<<<1, 256, 0, stream>>>(H, bbase, nblocks, nbuck);
    k3_scatter<<<nblocks, 256, 0, stream>>>(ei, e, H, staging, nblocks, nbuck);
    k4_finalize<<<nbuck, 256, 0, stream>>>(staging, bbase, row_ptr, dis, srcs, n);
    gemm_mfma<<<(n + 63) / 64, 256, 0, stream>>>(x, Wt, dis, xts, n);
    gather3<<<(n + 15) / 16, 256, 0, stream>>>(row_ptr, srcs, xts, dis, bias, out, n);
}

// Round 7
// 160.738 us; speedup vs baseline: 9.7035x; 1.4251x over previous
//
#include <hip/hip_runtime.h>

#define C 128
#define CHUNK 4096   // edges per K1/K3 block

typedef short bf16x8 __attribute__((ext_vector_type(8)));
typedef float f32x4 __attribute__((ext_vector_type(4)));

__device__ inline unsigned short f2bf(float f) {   // RNE f32 -> bf16
    unsigned u = __float_as_uint(f);
    u += 0x7fffu + ((u >> 16) & 1u);
    return (unsigned short)(u >> 16);
}

__device__ inline unsigned pk2bf(float lo, float hi) {
    return (unsigned)f2bf(lo) | ((unsigned)f2bf(hi) << 16);
}

// K1: per-chunk LDS histogram of dst>>8 -> H[bucket][block]; wcvt fused as
// trailing blocks (Wt[n][k] = bf16(W[k][n])).
__global__ __launch_bounds__(256) void k1_hist(
        const int* __restrict__ ei, int e, int* __restrict__ H,
        int nblocks, int nbuck,
        const float* __restrict__ W, unsigned short* __restrict__ Wt) {
    int b = blockIdx.x;
    int t = threadIdx.x;
    if (b >= nblocks) {   // wcvt: 64 blocks x 256 = 16384 elements
        int i = (b - nblocks) * 256 + t;
        int nn = i >> 7, k = i & 127;
        Wt[nn * 128 + k] = f2bf(W[k * 128 + nn]);
        return;
    }
    __shared__ int h[256];
    h[t] = 0;
    __syncthreads();
    int base = b * CHUNK;
    int lim = min(CHUNK, e - base);
    for (int i = t; i < lim; i += 256)
        atomicAdd(&h[ei[e + base + i] >> 8], 1);
    __syncthreads();
    if (t < nbuck) H[t * nblocks + b] = h[t];
}

// K2a: block g scans its bucket row H[g][0..nblocks) -> bucket-local
// exclusive offsets (in place); row total -> tot[g].  nblocks <= 256.
__global__ __launch_bounds__(256) void k2a_rowscan(
        int* __restrict__ H, int* __restrict__ tot, int nblocks) {
    __shared__ int s[256];
    int g = blockIdx.x, t = threadIdx.x;
    int v = (t < nblocks) ? H[g * nblocks + t] : 0;
    s[t] = v;
    __syncthreads();
    for (int off = 1; off < 256; off <<= 1) {
        int u = (t >= off) ? s[t - off] : 0;
        __syncthreads();
        s[t] += u;
        __syncthreads();
    }
    if (t < nblocks) H[g * nblocks + t] = s[t] - v;   // local exclusive
    if (t == 255) tot[g] = s[255];
}

// K2b: single block scans bucket totals -> bbase (exclusive), bbase[nbuck]=e.
__global__ __launch_bounds__(256) void k2b_bucketscan(
        const int* __restrict__ tot, int* __restrict__ bbase, int nbuck, int e) {
    __shared__ int s[256];
    int t = threadIdx.x;
    int v = (t < nbuck) ? tot[t] : 0;
    s[t] = v;
    __syncthreads();
    for (int off = 1; off < 256; off <<= 1) {
        int u = (t >= off) ? s[t - off] : 0;
        __syncthreads();
        s[t] += u;
        __syncthreads();
    }
    if (t < nbuck) bbase[t] = s[t] - v;
    if (t == 0) bbase[nbuck] = e;
}

// K3: rank edges by bucket via LDS cursors (cursor = bbase + local offset),
// write 4B records (dstlow:8)<<16 | src to per-block-disjoint contiguous runs.
__global__ __launch_bounds__(256) void k3_scatter(
        const int* __restrict__ ei, int e, const int* __restrict__ H,
        const int* __restrict__ bbase,
        unsigned* __restrict__ staging, int nblocks, int nbuck) {
    __shared__ int cur[256];
    int b = blockIdx.x, t = threadIdx.x;
    if (t < nbuck) cur[t] = bbase[t] + H[t * nblocks + b];
    __syncthreads();
    int base = b * CHUNK;
    int lim = min(CHUNK, e - base);
    for (int i = t; i < lim; i += 256) {
        int src = ei[base + i];
        int dst = ei[e + base + i];
        int pos = atomicAdd(&cur[dst >> 8], 1);
        staging[pos] = (unsigned)src | ((unsigned)(dst & 255) << 16);
    }
}

// K4: one block per bucket. LDS-count low bytes -> row_ptr, dis, then scatter
// src (ushort) into the bucket's own contiguous srcs region.
__global__ __launch_bounds__(256) void k4_finalize(
        const unsigned* __restrict__ staging, const int* __restrict__ bbase,
        int* __restrict__ row_ptr, float* __restrict__ dis,
        unsigned short* __restrict__ srcs, int n) {
    __shared__ int sc[256];
    __shared__ int cur[256];
    int g = blockIdx.x, t = threadIdx.x;
    int s0 = bbase[g], s1 = bbase[g + 1];
    sc[t] = 0;
    __syncthreads();
    for (int i = s0 + t; i < s1; i += 256)
        atomicAdd(&sc[staging[i] >> 16], 1);
    __syncthreads();
    int v = sc[t];
    __syncthreads();
    for (int off = 1; off < 256; off <<= 1) {
        int u = (t >= off) ? sc[t - off] : 0;
        __syncthreads();
        sc[t] += u;
        __syncthreads();
    }
    int excl = sc[t] - v;
    int idx = g * 256 + t;
    if (idx <= n) row_ptr[idx] = s0 + excl;
    if (idx < n) dis[idx] = rsqrtf((float)(v + 1));
    cur[t] = s0 + excl;
    __syncthreads();
    for (int i = s0 + t; i < s1; i += 256) {
        unsigned rec = staging[i];
        int pos = atomicAdd(&cur[rec >> 16], 1);
        srcs[pos] = (unsigned short)(rec & 0xffffu);
    }
}

// xts(bf16) = (x @ W) * dis[row], MFMA 16x16x32 bf16, LDS-free.
__global__ __launch_bounds__(256) void gemm_mfma(
        const float* __restrict__ x, const unsigned short* __restrict__ Wt,
        const float* __restrict__ dis, unsigned short* __restrict__ xts, int n) {
    const int lane = threadIdx.x & 63;
    const int wave = threadIdx.x >> 6;
    const int m = lane & 15;
    const int q = lane >> 4;
    const int r0 = blockIdx.x * 64 + wave * 16;
    const int row = r0 + m;
    const int rowc = (row < n) ? row : (n - 1);

    f32x4 acc[8];
#pragma unroll
    for (int nt = 0; nt < 8; ++nt) acc[nt] = (f32x4){0.f, 0.f, 0.f, 0.f};

#pragma unroll
    for (int kb = 0; kb < 4; ++kb) {
        const int k0 = kb * 32 + q * 8;
        const float4* xp = (const float4*)(x + (size_t)rowc * 128 + k0);
        float4 xa = xp[0];
        float4 xb = xp[1];
        union { unsigned u[4]; bf16x8 v; } af;
        af.u[0] = pk2bf(xa.x, xa.y);
        af.u[1] = pk2bf(xa.z, xa.w);
        af.u[2] = pk2bf(xb.x, xb.y);
        af.u[3] = pk2bf(xb.z, xb.w);
#pragma unroll
        for (int nt = 0; nt < 8; ++nt) {
            bf16x8 bf = *(const bf16x8*)(Wt + (size_t)(nt * 16 + m) * 128 + k0);
            acc[nt] = __builtin_amdgcn_mfma_f32_16x16x32_bf16(af.v, bf, acc[nt], 0, 0, 0);
        }
    }

    float dv[4];
    int gr[4];
#pragma unroll
    for (int r = 0; r < 4; ++r) {
        gr[r] = r0 + q * 4 + r;
        dv[r] = dis[(gr[r] < n) ? gr[r] : (n - 1)];
    }
#pragma unroll
    for (int nt = 0; nt < 8; ++nt) {
        int col = nt * 16 + m;
#pragma unroll
        for (int r = 0; r < 4; ++r) {
            if (gr[r] < n)
                xts[(size_t)gr[r] * 128 + col] = f2bf(acc[nt][r] * dv[r]);
        }
    }
}

__device__ inline void acc8(float* a, uint4 w) {
    a[0] += __uint_as_float(w.x << 16);
    a[1] += __uint_as_float(w.x & 0xffff0000u);
    a[2] += __uint_as_float(w.y << 16);
    a[3] += __uint_as_float(w.y & 0xffff0000u);
    a[4] += __uint_as_float(w.z << 16);
    a[5] += __uint_as_float(w.z & 0xffff0000u);
    a[6] += __uint_as_float(w.w << 16);
    a[7] += __uint_as_float(w.w & 0xffff0000u);
}

// out[i] = dis[i]*(xts[i] + sum_in xts[src]) + bias ; 16 lanes/node
__global__ void gather3(const int* __restrict__ row_ptr,
                        const unsigned short* __restrict__ srcs,
                        const unsigned short* __restrict__ xts,
                        const float* __restrict__ dis,
                        const float* __restrict__ bias, float* __restrict__ out, int n) {
    int node = blockIdx.x * 16 + (threadIdx.x >> 4);
    int q = threadIdx.x & 15;
    if (node >= n) return;
    const uint4* x4 = (const uint4*)xts;
    int start = row_ptr[node];
    int end = row_ptr[node + 1];
    float a0[8] = {0, 0, 0, 0, 0, 0, 0, 0};
    float a1[8] = {0, 0, 0, 0, 0, 0, 0, 0};
    acc8(a0, x4[node * 16 + q]);
    int j = start;
    for (; j + 4 <= end; j += 4) {
        uint4 m0 = x4[(int)srcs[j] * 16 + q];
        uint4 m1 = x4[(int)srcs[j + 1] * 16 + q];
        uint4 m2 = x4[(int)srcs[j + 2] * 16 + q];
        uint4 m3 = x4[(int)srcs[j + 3] * 16 + q];
        acc8(a0, m0);
        acc8(a1, m1);
        acc8(a0, m2);
        acc8(a1, m3);
    }
    for (; j < end; ++j) acc8(a0, x4[(int)srcs[j] * 16 + q]);
    float d = dis[node];
    const float4 b0 = ((const float4*)bias)[q * 2];
    const float4 b1 = ((const float4*)bias)[q * 2 + 1];
    float4 o0, o1;
    o0.x = (a0[0] + a1[0]) * d + b0.x;
    o0.y = (a0[1] + a1[1]) * d + b0.y;
    o0.z = (a0[2] + a1[2]) * d + b0.z;
    o0.w = (a0[3] + a1[3]) * d + b0.w;
    o1.x = (a0[4] + a1[4]) * d + b1.x;
    o1.y = (a0[5] + a1[5]) * d + b1.y;
    o1.z = (a0[6] + a1[6]) * d + b1.z;
    o1.w = (a0[7] + a1[7]) * d + b1.w;
    float4* op = (float4*)(out + node * 128 + q * 8);
    op[0] = o0;
    op[1] = o1;
}

extern "C" void kernel_launch(void* const* d_in, const int* in_sizes, int n_in,
                              void* d_out, int out_size, void* d_ws, size_t ws_size,
                              hipStream_t stream) {
    const float* x    = (const float*)d_in[0];
    const int*   ei   = (const int*)d_in[1];
    const float* W    = (const float*)d_in[2];
    const float* bias = (const float*)d_in[3];
    float* out = (float*)d_out;

    const int n = in_sizes[0] / C;             // 50000  (must be < 65536)
    const int e = in_sizes[1] / 2;             // 800000
    const int nblocks = (e + CHUNK - 1) / CHUNK;  // 196 (<=256)
    const int nbuck = (n + 255) >> 8;             // 196 (<=256)

    char* p = (char*)d_ws;
    auto alloc = [&](size_t bytes) {
        char* r = p;
        p += (bytes + 15) & ~(size_t)15;
        return (void*)r;
    };
    int*      H       = (int*)alloc((size_t)nbuck * nblocks * 4);
    int*      tot     = (int*)alloc(nbuck * 4);
    int*      bbase   = (int*)alloc((nbuck + 1) * 4);
    unsigned* staging = (unsigned*)alloc((size_t)e * 4);
    int*      row_ptr = (int*)alloc((n + 1) * 4);
    float*    dis     = (float*)alloc(n * 4);
    unsigned short* srcs = (unsigned short*)alloc((size_t)e * 2);
    unsigned short* xts  = (unsigned short*)alloc((size_t)n * C * 2);
    unsigned short* Wt   = (unsigned short*)alloc(128 * 128 * 2);

    k1_hist<<<nblocks + 64, 256, 0, stream>>>(ei, e, H, nblocks, nbuck, W, Wt);
    k2a_rowscan<<<nbuck, 256, 0, stream>>>(H, tot, nblocks);
    k2b_bucketscan<<<1, 256, 0, stream>>>(tot, bbase, nbuck, e);
    k3_scatter<<<nblocks, 256, 0, stream>>>(ei, e, H, bbase, staging, nblocks, nbuck);
    k4_finalize<<<nbuck, 256, 0, stream>>>(staging, bbase, row_ptr, dis, srcs, n);
    gemm_mfma<<<(n + 63) / 64, 256, 0, stream>>>(x, Wt, dis, xts, n);
    gather3<<<(n + 15) / 16, 256, 0, stream>>>(row_ptr, srcs, xts, dis, bias, out, n);
}